// Round 7
// baseline (268.637 us; speedup 1.0000x reference)
//
#include <hip/hip_runtime.h>

// CausalSelfAttention: B=2, T=4096, C=768, H=12, HD=64
// convert(x,w) -> QKV GEMM -> flash attention (QBLK=128/WG = 32 q/wave,
// split-KV for long blocks, single-buffer K/V w/ register prefetch, 32K LDS,
// S^T = K*Q^T, exp2 softmax w/ -m baked into acc init, defer-max)
// -> combine -> proj GEMM.

#define TSEQ 4096
#define NH 12
#define CDIM 768

typedef __bf16 bf16;
typedef __attribute__((ext_vector_type(8))) __bf16 bf16x8;
typedef __attribute__((ext_vector_type(4))) __bf16 bf16x4;
typedef __attribute__((ext_vector_type(4))) float f32x4;

__device__ __forceinline__ void gload16(const void* g, void* l) {
  __builtin_amdgcn_global_load_lds(
      (const __attribute__((address_space(1))) void*)g,
      (__attribute__((address_space(3))) void*)l, 16, 0, 0);
}

__device__ __forceinline__ float fexp2(float x) {
  return __builtin_amdgcn_exp2f(x);
}

#define MAX3(a, b, c) fmaxf(fmaxf((a), (b)), (c))

// ---------------------------------------------------------------- converts
__global__ void convert_x_kernel(const float* __restrict__ x,
                                 bf16* __restrict__ xb, int n) {
  int i = (blockIdx.x * blockDim.x + threadIdx.x) * 4;
  if (i < n) {
    float4 v = *(const float4*)(x + i);
    bf16x4 o;
    o[0] = (bf16)v.x; o[1] = (bf16)v.y; o[2] = (bf16)v.z; o[3] = (bf16)v.w;
    *(bf16x4*)(xb + i) = o;
  }
}

// src [R][Cc] f32 -> dst [Cc][R] bf16 (tiled transpose)
__global__ void transpose_w_kernel(const float* __restrict__ src,
                                   bf16* __restrict__ dst, int R, int Cc) {
  __shared__ float tile[32][33];
  int tx = threadIdx.x, ty = threadIdx.y;
  int c0 = blockIdx.x * 32, r0 = blockIdx.y * 32;
#pragma unroll
  for (int i = 0; i < 4; ++i)
    tile[ty + i * 8][tx] = src[(size_t)(r0 + ty + i * 8) * Cc + c0 + tx];
  __syncthreads();
#pragma unroll
  for (int i = 0; i < 4; ++i)
    dst[(size_t)(c0 + ty + i * 8) * R + r0 + tx] = (bf16)tile[tx][ty + i * 8];
}

// ---------------------------------------------------------------- GEMM
template <int MODE>
__global__ __launch_bounds__(256) void gemm_kernel(
    const bf16* __restrict__ A, const bf16* __restrict__ BT,
    const float* __restrict__ bias, bf16* __restrict__ qk_out,
    bf16* __restrict__ vT_out, float* __restrict__ c_out) {
  constexpr int K = 768;
  __shared__ alignas(16) bf16 As[128 * 64];
  __shared__ alignas(16) bf16 Bs[128 * 64];
  const int t = threadIdx.x;
  const int l = t & 63, w = t >> 6;
  const int l15 = l & 15, lg = l >> 4;
  const int nwg = gridDim.x * gridDim.y;
  int id = blockIdx.y * gridDim.x + blockIdx.x;
  id = (id & 7) * (nwg >> 3) + (id >> 3);
  const int m0 = (id / gridDim.x) << 7, n0 = (id % gridDim.x) << 7;
  const int wr = w >> 1, wc = w & 1;

  f32x4 acc[4][4] = {};

  const int r0 = t >> 3;
  const int kb8 = (((t & 7) ^ (r0 & 7)) << 3);
  const bf16* Asrc = A + (size_t)(m0 + r0) * K + kb8;
  const bf16* Bsrc = BT + (size_t)(n0 + r0) * K + kb8;

  for (int kt = 0; kt < K / 64; ++kt) {
#pragma unroll
    for (int i = 0; i < 4; ++i)
      gload16(Asrc + kt * 64 + (size_t)i * 32 * K, (char*)As + w * 1024 + i * 4096);
#pragma unroll
    for (int i = 0; i < 4; ++i)
      gload16(Bsrc + kt * 64 + (size_t)i * 32 * K, (char*)Bs + w * 1024 + i * 4096);
    __syncthreads();
#pragma unroll
    for (int kk = 0; kk < 2; ++kk) {
      bf16x8 af[4], bfv[4];
#pragma unroll
      for (int m = 0; m < 4; ++m) {
        int r = (wr << 6) + (m << 4) + l15;
        int kb = (kk << 2) + lg;
        af[m] = *(const bf16x8*)((const char*)As + r * 128 + ((kb ^ (r & 7)) << 4));
      }
#pragma unroll
      for (int n = 0; n < 4; ++n) {
        int r = (wc << 6) + (n << 4) + l15;
        int kb = (kk << 2) + lg;
        bfv[n] = *(const bf16x8*)((const char*)Bs + r * 128 + ((kb ^ (r & 7)) << 4));
      }
#pragma unroll
      for (int m = 0; m < 4; ++m)
#pragma unroll
        for (int n = 0; n < 4; ++n)
          acc[m][n] = __builtin_amdgcn_mfma_f32_16x16x32_bf16(af[m], bfv[n],
                                                              acc[m][n], 0, 0, 0);
    }
    __syncthreads();
  }

#pragma unroll
  for (int m = 0; m < 4; ++m) {
    int row = m0 + (wr << 6) + (m << 4) + (lg << 2);
    int b = row >> 12, tt = row & 4095;
#pragma unroll
    for (int n = 0; n < 4; ++n) {
      int col = n0 + (wc << 6) + (n << 4) + l15;
      float bv = bias[col];
      if (MODE == 0) {
        if (col < 1536) {
          float sc = (col < 768) ? 0.18033688011112042f : 1.0f;
          bf16* dst = qk_out + (size_t)(b * TSEQ + tt) * 1536 + col;
#pragma unroll
          for (int j = 0; j < 4; ++j)
            dst[(size_t)j * 1536] = (bf16)((acc[m][n][j] + bv) * sc);
        } else {
          int nl = col - 1536;
          bf16* dst = vT_out +
              ((size_t)(b * NH + (nl >> 6)) * 64 + (nl & 63)) * TSEQ + tt;
#pragma unroll
          for (int j = 0; j < 4; ++j) dst[j] = (bf16)(acc[m][n][j] + bv);
        }
      } else {
        float* dst = c_out + (size_t)row * 768 + col;
#pragma unroll
        for (int j = 0; j < 4; ++j) dst[(size_t)j * 768] = acc[m][n][j] + bv;
      }
    }
  }
}

// ---------------------------------------------------------------- attention
// QBLK=128 rows/WG (32/wave as 2 strips of 16).  Jobs: qb 0..15 unsplit
// (2qb+2 kv tiles); qb 16..31 split into two equal kv halves (qb+1 each).
// 32K LDS: Q/P [0,0x4000), K @0x4000, V @0x6000; reg-staged K/V prefetch.
// acc init = -mrun so P = exp2(acc) with no per-element subtract.
__global__ __launch_bounds__(256, 4) void attn_kernel(
    const bf16* __restrict__ qk,   // [B][T][1536], Q pre-scaled by log2e/8
    const bf16* __restrict__ vT,   // [B*NH][64][T]
    bf16* __restrict__ y,          // [B][T][768]
    bf16* __restrict__ opart,      // [384 sb][2 half][128 r][64 d]
    float* __restrict__ mlb) {     // [384][2][128 r][2 {m,l}]
  __shared__ alignas(16) char lds[32768];
  const int t = threadIdx.x;
  const int l = t & 63, w = t >> 6;
  const int l15 = l & 15, lg = l >> 4;

  // job decode: XCD x owns heads 3x..3x+2; j ascending = longest first
  const int rk = blockIdx.x;
  const int xcd = rk & 7, s = rk >> 3;
  const int bh = xcd * 3 + (s % 3);
  const int j = s / 3;  // 0..47
  int qb, kt0, kt1, half, split;
  if (j < 32) {  // split halves of qb 31..16
    qb = 31 - (j >> 1); half = j & 1; split = 1;
    int nh0 = qb + 1;
    kt0 = half ? nh0 : 0;
    kt1 = half ? 2 * qb + 2 : nh0;
  } else {       // unsplit qb 15..0
    qb = 47 - j; half = 0; split = 0;
    kt0 = 0; kt1 = 2 * qb + 2;
  }
  const int b = bh / NH, h = bh % NH;
  const bf16* qbase = qk + (size_t)b * TSEQ * 1536 + h * 64;
  const bf16* kbase = qbase + 768;
  const bf16* vbase = vT + (size_t)bh * 64 * TSEQ;

  const int r0 = t >> 3;
  const int kb8 = (((t & 7) ^ (r0 & 7)) << 3);
  const int q0 = qb << 7;
  const int qwmax = q0 + (w << 5) + 31;

  // hoisted per-lane LDS offsets (bytes)
  const int swz = l15 & 7;
  int koff[2];
  koff[0] = l15 * 128 + ((lg ^ swz) << 4);
  koff[1] = l15 * 128 + (((4 + lg) ^ swz) << 4);
  char* const preg = lds + w * 4096;  // wave-private P region (32 rows)
  int so[4];
#pragma unroll
  for (int m = 0; m < 4; ++m)
    so[m] = l15 * 128 + ((((m << 5) + (lg << 3)) ^ (swz << 4)));

  // prologue: Q tile [128][64] + K/V tile kt0
#pragma unroll
  for (int i = 0; i < 4; ++i)
    gload16(qbase + (size_t)(q0 + i * 32 + r0) * 1536 + kb8,
            lds + w * 1024 + i * 4096);
#pragma unroll
  for (int i = 0; i < 2; ++i) {
    gload16(kbase + (size_t)(kt0 * 64 + i * 32 + r0) * 1536 + kb8,
            lds + 0x4000 + w * 1024 + i * 4096);
    gload16(vbase + (size_t)(i * 32 + r0) * TSEQ + kt0 * 64 + kb8,
            lds + 0x6000 + w * 1024 + i * 4096);
  }
  // register prefetch of tile kt0+1
  const bf16* ksrc = kbase + (size_t)((kt0 + 1) * 64 + r0) * 1536 + kb8;
  const bf16* vsrc = vbase + (size_t)r0 * TSEQ + (kt0 + 1) * 64 + kb8;
  int4 kr0, kr1, vr0, vr1;
  if (kt0 + 1 < kt1) {
    kr0 = *(const int4*)(ksrc);
    kr1 = *(const int4*)(ksrc + (size_t)32 * 1536);
    vr0 = *(const int4*)(vsrc);
    vr1 = *(const int4*)(vsrc + (size_t)32 * TSEQ);
    ksrc += (size_t)64 * 1536;
    vsrc += 64;
  }
  __syncthreads();

  // Q fragments: strips n=0,1 rows w*32 + n*16 + l15
  bf16x8 qf[2][2];
#pragma unroll
  for (int n = 0; n < 2; ++n)
#pragma unroll
    for (int kk = 0; kk < 2; ++kk) {
      int r = (w << 5) + (n << 4) + l15;
      int kb = (kk << 2) + lg;
      qf[n][kk] = *(const bf16x8*)(lds + r * 128 + ((kb ^ (r & 7)) << 4));
    }

  f32x4 o[2][4] = {};
  float mrun[2] = {0.f, 0.f};
  float lrun[2] = {0.f, 0.f};

  for (int kt = kt0; kt < kt1; ++kt) {
    const int kv0 = kt << 6;

    if (kv0 <= qwmax) {
      // S^T - m: acc init = -mrun[n]
      f32x4 s4[2][4];
#pragma unroll
      for (int n = 0; n < 2; ++n) {
        float mi = -mrun[n];
#pragma unroll
        for (int m = 0; m < 4; ++m) {
          s4[n][m][0] = mi; s4[n][m][1] = mi; s4[n][m][2] = mi; s4[n][m][3] = mi;
        }
      }
      __builtin_amdgcn_s_setprio(1);
#pragma unroll
      for (int kk = 0; kk < 2; ++kk) {
        bf16x8 kf[4];
#pragma unroll
        for (int m = 0; m < 4; ++m)
          kf[m] = *(const bf16x8*)(lds + 0x4000 + koff[kk] + m * 2048);
#pragma unroll
        for (int m = 0; m < 4; ++m)
#pragma unroll
          for (int n = 0; n < 2; ++n)
            s4[n][m] = __builtin_amdgcn_mfma_f32_16x16x32_bf16(
                kf[m], qf[n][kk], s4[n][m], 0, 0, 0);
      }
      __builtin_amdgcn_s_setprio(0);

      if (kv0 + 63 > q0 + (w << 5)) {  // diagonal: per-element causal mask
#pragma unroll
        for (int n = 0; n < 2; ++n) {
          int qn = q0 + (w << 5) + (n << 4) + l15;
#pragma unroll
          for (int m = 0; m < 4; ++m) {
            int kvr = kv0 + (m << 4) + (lg << 2);
#pragma unroll
            for (int jj = 0; jj < 4; ++jj)
              if (kvr + jj > qn) s4[n][m][jj] = -__builtin_inff();
          }
        }
      }
      // per-strip relative max (acc already has -m baked in)
      float cm[2];
#pragma unroll
      for (int n = 0; n < 2; ++n) {
        float t0 = MAX3(s4[n][0][0], s4[n][0][1], s4[n][0][2]);
        float t1 = MAX3(s4[n][0][3], s4[n][1][0], s4[n][1][1]);
        float t2 = MAX3(s4[n][1][2], s4[n][1][3], s4[n][2][0]);
        float t3 = MAX3(s4[n][2][1], s4[n][2][2], s4[n][2][3]);
        float t4 = MAX3(s4[n][3][0], s4[n][3][1], s4[n][3][2]);
        float c = MAX3(MAX3(t0, t1, s4[n][3][3]), fmaxf(t2, t3), t4);
        c = fmaxf(c, __shfl_xor(c, 16));
        cm[n] = fmaxf(c, __shfl_xor(c, 32));
      }
      // defer-max: rescale only when relative max exceeds THR=8
      if (__any((cm[0] > 8.f) || (cm[1] > 8.f))) {
#pragma unroll
        for (int n = 0; n < 2; ++n) {
          float delta = fmaxf(cm[n], 0.f);
          float alpha = fexp2(-delta);
          mrun[n] += delta;
          lrun[n] *= alpha;
#pragma unroll
          for (int jj = 0; jj < 4; ++jj) {
            int rr = (lg << 2) + jj;
            float a = __shfl(alpha, (l & 48) | rr);
#pragma unroll
            for (int no = 0; no < 4; ++no) o[n][no][jj] *= a;
          }
#pragma unroll
          for (int m = 0; m < 4; ++m)
#pragma unroll
            for (int jj = 0; jj < 4; ++jj) s4[n][m][jj] -= delta;
        }
      }
      // P = exp2(acc); per-strip column sums; write P to LDS
#pragma unroll
      for (int n = 0; n < 2; ++n) {
        float ps = 0.f;
#pragma unroll
        for (int m = 0; m < 4; ++m) {
          bf16x4 pv;
#pragma unroll
          for (int jj = 0; jj < 4; ++jj) {
            float p = fexp2(s4[n][m][jj]);
            pv[jj] = (bf16)p;
            ps += p;
          }
          *(bf16x4*)(preg + (n << 11) + so[m]) = pv;
        }
        ps += __shfl_xor(ps, 16);
        ps += __shfl_xor(ps, 32);
        lrun[n] += ps;
      }
      // PV: O[q][d] += P[q][kv] * V[kv][d]
      __builtin_amdgcn_s_setprio(1);
#pragma unroll
      for (int kk = 0; kk < 2; ++kk) {
        bf16x8 vbv[4];
#pragma unroll
        for (int no = 0; no < 4; ++no)
          vbv[no] = *(const bf16x8*)(lds + 0x6000 + koff[kk] + no * 2048);
#pragma unroll
        for (int n = 0; n < 2; ++n) {
          bf16x8 pa = *(const bf16x8*)(preg + (n << 11) + koff[kk]);
#pragma unroll
          for (int no = 0; no < 4; ++no)
            o[n][no] = __builtin_amdgcn_mfma_f32_16x16x32_bf16(
                pa, vbv[no], o[n][no], 0, 0, 0);
        }
      }
      __builtin_amdgcn_s_setprio(0);
    }

    if (kt + 1 < kt1) {
      __syncthreads();  // all waves done reading K/V
      *(int4*)(lds + 0x4000 + t * 16) = kr0;
      *(int4*)(lds + 0x4000 + 4096 + t * 16) = kr1;
      *(int4*)(lds + 0x6000 + t * 16) = vr0;
      *(int4*)(lds + 0x6000 + 4096 + t * 16) = vr1;
      if (kt + 2 < kt1) {  // issue loads for tile kt+2
        kr0 = *(const int4*)(ksrc);
        kr1 = *(const int4*)(ksrc + (size_t)32 * 1536);
        vr0 = *(const int4*)(vsrc);
        vr1 = *(const int4*)(vsrc + (size_t)32 * TSEQ);
        ksrc += (size_t)64 * 1536;
        vsrc += 64;
      }
      __syncthreads();  // new tile visible
    }
  }

  // epilogue
  if (!split) {
#pragma unroll
    for (int n = 0; n < 2; ++n)
#pragma unroll
      for (int jj = 0; jj < 4; ++jj) {
        int rr = (lg << 2) + jj;
        float lv = __shfl(lrun[n], (l & 48) | rr);
        float linv = __builtin_amdgcn_rcpf(lv);
        int qrow = q0 + (w << 5) + (n << 4) + rr;
        size_t base = ((size_t)(b * TSEQ + qrow)) * 768 + h * 64;
#pragma unroll
        for (int no = 0; no < 4; ++no)
          y[base + (no << 4) + l15] = (bf16)(o[n][no][jj] * linv);
      }
  } else {
    const int sb2 = (bh * 16 + (qb - 16)) * 2 + half;
#pragma unroll
    for (int n = 0; n < 2; ++n)
#pragma unroll
      for (int jj = 0; jj < 4; ++jj) {
        int rr = (lg << 2) + jj;
        float lv = __shfl(lrun[n], (l & 48) | rr);
        float linv = __builtin_amdgcn_rcpf(lv);
        int r = (w << 5) + (n << 4) + rr;
        size_t base = ((size_t)sb2 * 128 + r) * 64;
#pragma unroll
        for (int no = 0; no < 4; ++no)
          opart[base + (no << 4) + l15] = (bf16)(o[n][no][jj] * linv);
      }
    if (l < 16) {
#pragma unroll
      for (int n = 0; n < 2; ++n) {
        size_t mi = ((size_t)sb2 * 128 + (w << 5) + (n << 4) + l) * 2;
        mlb[mi] = mrun[n];
        mlb[mi + 1] = lrun[n];
      }
    }
  }
}

// ---------------------------------------------------------------- combine
__global__ void combine_kernel(const bf16* __restrict__ op,
                               const float* __restrict__ ml,
                               bf16* __restrict__ y) {
  int g = blockIdx.x * 256 + threadIdx.x;  // 786432 total
  int d4 = (g & 15) << 2;
  int rid = g >> 4;        // 0..49151
  int rr = rid & 127;
  int sb = rid >> 7;       // 0..383
  int bh = sb >> 4, qb = 16 + (sb & 15);
  int b = bh / NH, h = bh % NH;
  size_t m0i = ((size_t)(sb * 2) * 128 + rr) * 2;
  size_t m1i = ((size_t)(sb * 2 + 1) * 128 + rr) * 2;
  float m0 = ml[m0i], l0 = ml[m0i + 1];
  float m1 = ml[m1i], l1 = ml[m1i + 1];
  float M = fmaxf(m0, m1);
  float w0 = fexp2(m0 - M) * l0, w1 = fexp2(m1 - M) * l1;
  float inv = 1.f / (w0 + w1);
  w0 *= inv; w1 *= inv;
  const bf16* o0 = op + (((size_t)(sb * 2) * 128 + rr) * 64 + d4);
  const bf16* o1 = op + (((size_t)(sb * 2 + 1) * 128 + rr) * 64 + d4);
  bf16x4 a = *(const bf16x4*)o0, c = *(const bf16x4*)o1;
  bf16x4 out;
#pragma unroll
  for (int jj = 0; jj < 4; ++jj)
    out[jj] = (bf16)(w0 * (float)a[jj] + w1 * (float)c[jj]);
  int qrow = (qb << 7) + rr;
  *(bf16x4*)(y + ((size_t)(b * TSEQ + qrow)) * 768 + h * 64 + d4) = out;
}

// ---------------------------------------------------------------- launch
extern "C" void kernel_launch(void* const* d_in, const int* in_sizes, int n_in,
                              void* d_out, int out_size, void* d_ws,
                              size_t ws_size, hipStream_t stream) {
  const float* x = (const float*)d_in[0];
  const float* w_qkv = (const float*)d_in[1];
  const float* b_qkv = (const float*)d_in[2];
  const float* w_proj = (const float*)d_in[3];
  const float* b_proj = (const float*)d_in[4];
  float* out = (float*)d_out;
  char* ws = (char*)d_ws;

  bf16* xb     = (bf16*)(ws);             // 12.58M; reused as opart in attn
  bf16* wqkvT  = (bf16*)(ws + 12582912);
  bf16* wprojT = (bf16*)(ws + 16121856);
  bf16* qkbuf  = (bf16*)(ws + 17301504);
  bf16* vTbuf  = (bf16*)(ws + 42467328);
  bf16* ybuf   = (bf16*)(ws + 55050240);
  float* mlb   = (float*)(ws + 67633152); // 0.79M

  convert_x_kernel<<<6144, 256, 0, stream>>>(x, xb, 2 * TSEQ * CDIM);
  transpose_w_kernel<<<dim3(72, 24), dim3(32, 8), 0, stream>>>(w_qkv, wqkvT, 768, 2304);
  transpose_w_kernel<<<dim3(24, 24), dim3(32, 8), 0, stream>>>(w_proj, wprojT, 768, 768);
  gemm_kernel<0><<<dim3(18, 64), 256, 0, stream>>>(xb, wqkvT, b_qkv, qkbuf, vTbuf, nullptr);
  attn_kernel<<<1152, 256, 0, stream>>>(qkbuf, vTbuf, ybuf, xb, mlb);
  combine_kernel<<<3072, 256, 0, stream>>>(xb, mlb, ybuf);
  gemm_kernel<1><<<dim3(6, 64), 256, 0, stream>>>(ybuf, wprojT, b_proj, nullptr, nullptr, out);
}